// Round 1
// baseline (641.121 us; speedup 1.0000x reference)
//
#include <hip/hip_runtime.h>

#define H 4096
#define NVOCAB 256
#define NE 8   // gate elements per block

// One block (6 waves) per NE consecutive gate elements.
// Waves 0..2: W_ih rows {g*H+i} . x ; waves 3..5: W_hh rows . h.
// Each wave keeps the 16 KB operand vector in 16 float4 registers (loaded
// once, reused for all NE rows) and streams weight rows in 8-deep float4
// bursts so ~8-16 outstanding 1 KB loads/wave hide HBM latency.
__global__ __launch_bounds__(384, 3) void gru_layer_kernel(
    const float* __restrict__ Wih,
    const float* __restrict__ Whh,
    const float* __restrict__ bih,
    const float* __restrict__ bhh,
    const float* __restrict__ xbase,   // emb (layer0) or h0' (layer1)
    const int* __restrict__ inp, int use_inp,
    const float* __restrict__ hprev,
    float* __restrict__ hout)
{
    __shared__ float part[6][NE];
    const int wave = threadIdx.x >> 6;   // 0..5
    const int lane = threadIdx.x & 63;
    const int i0   = blockIdx.x * NE;

    const float* x = xbase + (use_inp ? (size_t)inp[0] * H : 0);
    const int g = (wave < 3) ? wave : (wave - 3);       // gate r/z/n
    const float* W    = (wave < 3) ? Wih : Whh;
    const float* vec  = (wave < 3) ? x   : hprev;
    const float* bias = (wave < 3) ? bih : bhh;

    // Operand vector -> registers, once per wave (64 VGPRs).
    const float4* xr = reinterpret_cast<const float4*>(vec);
    float4 v[16];
#pragma unroll
    for (int it = 0; it < 16; ++it) v[it] = xr[it * 64 + lane];

    for (int e = 0; e < NE; ++e) {
        const int i = i0 + e;
        const float4* wr =
            reinterpret_cast<const float4*>(W + (size_t)(g * H + i) * H);
        float ax = 0.f, ay = 0.f, az = 0.f, aw = 0.f;
#pragma unroll
        for (int half = 0; half < 2; ++half) {
            float4 w[8];
#pragma unroll
            for (int j = 0; j < 8; ++j)
                w[j] = wr[half * 512 + j * 64 + lane];   // 8 loads in flight
#pragma unroll
            for (int j = 0; j < 8; ++j) {
                ax += w[j].x * v[half * 8 + j].x;
                ay += w[j].y * v[half * 8 + j].y;
                az += w[j].z * v[half * 8 + j].z;
                aw += w[j].w * v[half * 8 + j].w;
            }
        }
        float acc = (ax + ay) + (az + aw);
#pragma unroll
        for (int off = 32; off > 0; off >>= 1) acc += __shfl_down(acc, off, 64);
        if (lane == 0) part[wave][e] = acc + bias[g * H + i];
    }
    __syncthreads();

    if (threadIdx.x < NE) {
        const int e = threadIdx.x;
        const int i = i0 + e;
        float ir = part[0][e], iz = part[1][e], inn = part[2][e];
        float hr = part[3][e], hz = part[4][e], hn  = part[5][e];
        float r = 1.f / (1.f + __expf(-(ir + hr)));
        float z = 1.f / (1.f + __expf(-(iz + hz)));
        float n = tanhf(inn + r * hn);
        float h = hprev[i];
        hout[i] = (1.f - z) * n + z * h;
    }
}

// Decoder: 256 rows of W_dec . h1' + b_dec. One wave per row, batched loads.
__global__ __launch_bounds__(256) void dec_kernel(
    const float* __restrict__ Wdec,
    const float* __restrict__ bdec,
    const float* __restrict__ vec,
    float* __restrict__ out)
{
    const int wave = threadIdx.x >> 6;
    const int lane = threadIdx.x & 63;
    const int row = blockIdx.x * 4 + wave;   // 64 blocks -> 256 rows
    const float4* wr = reinterpret_cast<const float4*>(Wdec + (size_t)row * H);
    const float4* xr = reinterpret_cast<const float4*>(vec);
    float ax = 0.f, ay = 0.f, az = 0.f, aw = 0.f;
#pragma unroll
    for (int q = 0; q < 2; ++q) {
        float4 w[8], xv[8];
#pragma unroll
        for (int j = 0; j < 8; ++j) {
            w[j]  = wr[q * 512 + j * 64 + lane];
            xv[j] = xr[q * 512 + j * 64 + lane];
        }
#pragma unroll
        for (int j = 0; j < 8; ++j) {
            ax += w[j].x * xv[j].x;
            ay += w[j].y * xv[j].y;
            az += w[j].z * xv[j].z;
            aw += w[j].w * xv[j].w;
        }
    }
    float acc = (ax + ay) + (az + aw);
#pragma unroll
    for (int off = 32; off > 0; off >>= 1) acc += __shfl_down(acc, off, 64);
    if (lane == 0) out[row] = acc + bdec[row];
}

extern "C" void kernel_launch(void* const* d_in, const int* in_sizes, int n_in,
                              void* d_out, int out_size, void* d_ws, size_t ws_size,
                              hipStream_t stream) {
    // setup_inputs() order (all float32 except inp which is int32):
    // 0 inp(1) 1 hidden(2*4096) 2 emb(256*4096)
    // 3 W_ih0 4 W_hh0 5 b_ih0 6 b_hh0
    // 7 W_ih1 8 W_hh1 9 b_ih1 10 b_hh1
    // 11 W_dec 12 b_dec
    const int*   inp    = (const int*)d_in[0];
    const float* hidden = (const float*)d_in[1];
    const float* emb    = (const float*)d_in[2];
    const float* Wih0   = (const float*)d_in[3];
    const float* Whh0   = (const float*)d_in[4];
    const float* bih0   = (const float*)d_in[5];
    const float* bhh0   = (const float*)d_in[6];
    const float* Wih1   = (const float*)d_in[7];
    const float* Whh1   = (const float*)d_in[8];
    const float* bih1   = (const float*)d_in[9];
    const float* bhh1   = (const float*)d_in[10];
    const float* Wdec   = (const float*)d_in[11];
    const float* bdec   = (const float*)d_in[12];

    float* out = (float*)d_out;  // [256 logits][h0' 4096][h1' 4096]
    float* h0o = out + NVOCAB;
    float* h1o = out + NVOCAB + H;

    // layer 0: x = emb[inp[0]], hprev = hidden[0] -> h0'
    gru_layer_kernel<<<H / NE, 384, 0, stream>>>(
        Wih0, Whh0, bih0, bhh0, emb, inp, 1, hidden, h0o);
    // layer 1: x = h0', hprev = hidden[1] -> h1'
    gru_layer_kernel<<<H / NE, 384, 0, stream>>>(
        Wih1, Whh1, bih1, bhh1, h0o, inp, 0, hidden + H, h1o);
    // decoder logits
    dec_kernel<<<NVOCAB / 4, 256, 0, stream>>>(Wdec, bdec, h1o, out);
}

// Round 2
// 638.841 us; speedup vs baseline: 1.0036x; 1.0036x over previous
//
#include <hip/hip_runtime.h>

#define H 4096
#define NVOCAB 256
#define NE 8          // gate elements per block
#define NTHREADS 768  // 12 waves: 6 (matrix,gate) pairs x 2 half-rows

// One block per NE consecutive gate elements.
// Wave w: pair p = w>>1 (p<3: W_ih gate p vs x ; p>=3: W_hh gate p-3 vs h),
//         half = w&1 (which 2048-elem half of the row).
// Operand vectors x,h staged ONCE into LDS (32 KB); each task is 8
// independent float4 global loads (8 KB in flight per wave, 32 VGPRs) so
// 24 waves/CU keep ~192 KB of misses outstanding.
__global__ __launch_bounds__(NTHREADS, 6) void gru_layer_kernel(
    const float* __restrict__ Wih,
    const float* __restrict__ Whh,
    const float* __restrict__ bih,
    const float* __restrict__ bhh,
    const float* __restrict__ xbase,   // emb (layer0) or h0' (layer1)
    const int* __restrict__ inp, int use_inp,
    const float* __restrict__ hprev,
    float* __restrict__ hout)
{
    __shared__ float4 vlds[2][H / 4];       // [0]=x, [1]=h   (32 KB)
    __shared__ float part[6][2][NE];

    const int tid  = threadIdx.x;
    const int wave = tid >> 6;              // 0..11
    const int lane = tid & 63;
    const int i0   = blockIdx.x * NE;

    const float* x = xbase + (use_inp ? (size_t)inp[0] * H : 0);

    // ---- stage x and h into LDS (1024 float4 each) ----
    const float4* xr = reinterpret_cast<const float4*>(x);
    const float4* hr = reinterpret_cast<const float4*>(hprev);
    for (int idx = tid; idx < H / 4; idx += NTHREADS) {
        vlds[0][idx] = xr[idx];
        vlds[1][idx] = hr[idx];
    }
    __syncthreads();

    const int p    = wave >> 1;             // 0..5
    const int half = wave & 1;              // 0/1
    const int g    = (p < 3) ? p : p - 3;   // gate r/z/n
    const float*  W  = (p < 3) ? Wih : Whh;
    const float4* vl = &vlds[(p < 3) ? 0 : 1][half * 512];

    const float4* wbase = reinterpret_cast<const float4*>(
        W + (size_t)(g * H + i0) * H) + half * 512;

    for (int e = 0; e < NE; ++e) {
        const float4* wr = wbase + (size_t)e * (H / 4);
        float4 w[8];
#pragma unroll
        for (int j = 0; j < 8; ++j)
            w[j] = wr[j * 64 + lane];        // 8 loads in flight, 32 VGPRs
        float ax = 0.f, ay = 0.f, az = 0.f, aw = 0.f;
#pragma unroll
        for (int j = 0; j < 8; ++j) {
            float4 v = vl[j * 64 + lane];    // LDS, overlapped via lgkmcnt
            ax += w[j].x * v.x; ay += w[j].y * v.y;
            az += w[j].z * v.z; aw += w[j].w * v.w;
        }
        float acc = (ax + ay) + (az + aw);
#pragma unroll
        for (int off = 32; off > 0; off >>= 1) acc += __shfl_down(acc, off, 64);
        if (lane == 0) part[p][half][e] = acc;
        // next-iteration loads issue into freed w[] regs while reduce runs
    }
    __syncthreads();

    if (tid < NE) {
        const int e = tid, i = i0 + e;
        float ir = part[0][0][e] + part[0][1][e] + bih[0 * H + i];
        float iz = part[1][0][e] + part[1][1][e] + bih[1 * H + i];
        float in_= part[2][0][e] + part[2][1][e] + bih[2 * H + i];
        float hrv= part[3][0][e] + part[3][1][e] + bhh[0 * H + i];
        float hz = part[4][0][e] + part[4][1][e] + bhh[1 * H + i];
        float hn = part[5][0][e] + part[5][1][e] + bhh[2 * H + i];
        float r = 1.f / (1.f + __expf(-(ir + hrv)));
        float z = 1.f / (1.f + __expf(-(iz + hz)));
        float n = tanhf(in_ + r * hn);
        float h = hprev[i];
        hout[i] = (1.f - z) * n + z * h;
    }
}

// Decoder: 256 rows of W_dec . h1' + b_dec. One wave per row, batched loads.
__global__ __launch_bounds__(256) void dec_kernel(
    const float* __restrict__ Wdec,
    const float* __restrict__ bdec,
    const float* __restrict__ vec,
    float* __restrict__ out)
{
    const int wave = threadIdx.x >> 6;
    const int lane = threadIdx.x & 63;
    const int row = blockIdx.x * 4 + wave;   // 64 blocks -> 256 rows
    const float4* wr = reinterpret_cast<const float4*>(Wdec + (size_t)row * H);
    const float4* xr = reinterpret_cast<const float4*>(vec);
    float ax = 0.f, ay = 0.f, az = 0.f, aw = 0.f;
#pragma unroll
    for (int q = 0; q < 2; ++q) {
        float4 w[8], xv[8];
#pragma unroll
        for (int j = 0; j < 8; ++j) {
            w[j]  = wr[q * 512 + j * 64 + lane];
            xv[j] = xr[q * 512 + j * 64 + lane];
        }
#pragma unroll
        for (int j = 0; j < 8; ++j) {
            ax += w[j].x * xv[j].x;
            ay += w[j].y * xv[j].y;
            az += w[j].z * xv[j].z;
            aw += w[j].w * xv[j].w;
        }
    }
    float acc = (ax + ay) + (az + aw);
#pragma unroll
    for (int off = 32; off > 0; off >>= 1) acc += __shfl_down(acc, off, 64);
    if (lane == 0) out[row] = acc + bdec[row];
}

extern "C" void kernel_launch(void* const* d_in, const int* in_sizes, int n_in,
                              void* d_out, int out_size, void* d_ws, size_t ws_size,
                              hipStream_t stream) {
    // setup_inputs() order (all float32 except inp which is int32):
    // 0 inp(1) 1 hidden(2*4096) 2 emb(256*4096)
    // 3 W_ih0 4 W_hh0 5 b_ih0 6 b_hh0
    // 7 W_ih1 8 W_hh1 9 b_ih1 10 b_hh1
    // 11 W_dec 12 b_dec
    const int*   inp    = (const int*)d_in[0];
    const float* hidden = (const float*)d_in[1];
    const float* emb    = (const float*)d_in[2];
    const float* Wih0   = (const float*)d_in[3];
    const float* Whh0   = (const float*)d_in[4];
    const float* bih0   = (const float*)d_in[5];
    const float* bhh0   = (const float*)d_in[6];
    const float* Wih1   = (const float*)d_in[7];
    const float* Whh1   = (const float*)d_in[8];
    const float* bih1   = (const float*)d_in[9];
    const float* bhh1   = (const float*)d_in[10];
    const float* Wdec   = (const float*)d_in[11];
    const float* bdec   = (const float*)d_in[12];

    float* out = (float*)d_out;  // [256 logits][h0' 4096][h1' 4096]
    float* h0o = out + NVOCAB;
    float* h1o = out + NVOCAB + H;

    // layer 0: x = emb[inp[0]], hprev = hidden[0] -> h0'
    gru_layer_kernel<<<H / NE, NTHREADS, 0, stream>>>(
        Wih0, Whh0, bih0, bhh0, emb, inp, 1, hidden, h0o);
    // layer 1: x = h0', hprev = hidden[1] -> h1'
    gru_layer_kernel<<<H / NE, NTHREADS, 0, stream>>>(
        Wih1, Whh1, bih1, bhh1, h0o, inp, 0, hidden + H, h1o);
    // decoder logits
    dec_kernel<<<NVOCAB / 4, 256, 0, stream>>>(Wdec, bdec, h1o, out);
}